// Round 12
// baseline (54.730 us; speedup 1.0000x reference)
//
#include <hip/hip_runtime.h>

#define THREADS 256
#define WPB 4
#define ROW_LEN 512
#define NB 2048            // grid-stride block count: 2048*4 waves = 8192 wave slots

typedef float f4 __attribute__((ext_vector_type(4)));
typedef char  c8 __attribute__((ext_vector_type(8)));

__device__ __forceinline__ float wave_reduce_max(float v) {
#pragma unroll
    for (int o = 32; o > 0; o >>= 1) v = fmaxf(v, __shfl_xor(v, o));
    return v;
}
__device__ __forceinline__ float wave_reduce_sum(float v) {
#pragma unroll
    for (int o = 32; o > 0; o >>= 1) v += __shfl_xor(v, o);
    return v;
}

// pass 0: only reader of scores. Software-pipelined grid-stride loop: next
// iteration's global loads are issued BEFORE this iteration's reduce chains,
// keeping the read stream busy under the cross-lane latency.
__global__ __launch_bounds__(THREADS) void pla_pass0(
    const float* __restrict__ scores,
    const float* __restrict__ coeffs_m,
    const float* __restrict__ coeffs_c,
    const float* __restrict__ intervals,
    char* __restrict__ svq,            // [nrows*512] s8
    float* __restrict__ rowg,          // [nrows] g_r
    float* __restrict__ slots,         // [NB], fully overwritten
    int nrows)
{
    __shared__ float2 s_mc[12];
    __shared__ float  s_a[13];         // interval lower edges + inf guard
    __shared__ float  s_bm[WPB];

    const int tid = threadIdx.x;
    if (tid < 12) {
        s_mc[tid] = make_float2(coeffs_m[tid], coeffs_c[tid]);
        s_a[tid]  = intervals[tid];
    }
    if (tid == 12) s_a[12] = __builtin_inff();
    __syncthreads();

    const int wave = tid >> 6;
    const int lane = tid & 63;

    const float c10 = coeffs_c[10];
    const float k0  = 127.0f / c10;

    const int ngroups = (nrows + WPB - 1) / WPB;
    float bmax = 0.0f;                                  // per-wave (lane0) candidate

    int g = blockIdx.x;
    if (g < ngroups) {
        int row   = g * WPB + wave;
        bool act  = row < nrows;                        // wave-uniform
        float4 v0 = {}, v1 = {};
        if (act) {
            const float4* rp = reinterpret_cast<const float4*>(scores + (size_t)row * ROW_LEN);
            v0 = rp[lane];
            v1 = rp[lane + 64];
        }
        while (true) {
            // ---- prefetch next row-group (issues loads before compute) ----
            const int gn   = g + NB;
            const int rown = gn * WPB + wave;
            const bool actn = (gn < ngroups) && (rown < nrows);
            float4 n0 = {}, n1 = {};
            if (actn) {
                const float4* rpn = reinterpret_cast<const float4*>(scores + (size_t)rown * ROW_LEN);
                n0 = rpn[lane];
                n1 = rpn[lane + 64];
            }
            // ---- compute current row ----
            if (act) {
                float x[8] = {v0.x, v0.y, v0.z, v0.w, v1.x, v1.y, v1.z, v1.w};

                float mx = fmaxf(fmaxf(fmaxf(x[0], x[1]), fmaxf(x[2], x[3])),
                                 fmaxf(fmaxf(x[4], x[5]), fmaxf(x[6], x[7])));
                mx = wave_reduce_max(mx);

                float e[8];
                float sum = 0.0f;
#pragma unroll
                for (int j = 0; j < 8; ++j) {
                    float sh = x[j] - mx;                   // <= 0; |sh| < 32 here
                    float t = rintf(sh * 67108864.0f);      // Q32.26 snap (2^31 clamp never binds)
                    float fx = t * 1.4901161193847656e-8f;  // * 2^-26 exact
                    float xc = fmaxf(fx, -10.0f);           // fx <= 0 structurally

                    // exact searchsorted: uniform-width guess + edge-table correction
                    int gi = (int)((xc + 10.0f) * 1.2f);
                    gi = min(max(gi, 0), 11);
                    if (xc < s_a[gi])            gi -= 1;
                    else if (xc >= s_a[gi + 1])  gi += 1;
                    int idx = min(gi, 10);                  // reference clamp to len-2

                    float2 p = s_mc[idx];
                    float ev = p.x * xc + p.y;
                    e[j] = ev;
                    sum += ev;
                }
                sum = wave_reduce_sum(sum);
                const float inv = 1.0f / (sum + 1e-9f);

                c8 q;
#pragma unroll
                for (int j = 0; j < 8; ++j) q[j] = (char)(int)rintf(e[j] * k0);
                reinterpret_cast<c8*>(svq + (size_t)row * ROW_LEN)[lane] = q;

                if (lane == 0) {
                    rowg[row] = c10 * inv * (1.0f / 127.0f);
                    bmax = fmaxf(bmax, c10 * inv);          // row absmax candidate
                }
            }
            if (gn >= ngroups) break;
            g = gn; row = rown; act = actn; v0 = n0; v1 = n1;
        }
    }

    if (lane == 0) s_bm[wave] = bmax;
    __syncthreads();
    if (tid == 0) {
        float bm = fmaxf(fmaxf(s_bm[0], s_bm[1]), fmaxf(s_bm[2], s_bm[3]));
        slots[blockIdx.x] = bm;
    }
}

// pass 1: prologue reduces slots[NB] block-locally -> scale; software-pipelined
// grid-stride: s8 -> q = clamp(rint(s8 * g_r * iscale)) -> nt-store q*scale.
__global__ __launch_bounds__(THREADS) void pla_pass1(
    const char* __restrict__ svq,
    const float* __restrict__ rowg,
    const float* __restrict__ slots,
    float* __restrict__ out,
    int nrows)
{
    __shared__ float s_red[WPB];
    const int tid  = threadIdx.x;
    const int wave = tid >> 6;
    const int lane = tid & 63;

    // block-local global-absmax reduce (identical result in every block)
    float m = 0.0f;
    for (int i = tid; i < NB; i += THREADS) m = fmaxf(m, slots[i]);
    m = wave_reduce_max(m);
    if (lane == 0) s_red[wave] = m;
    __syncthreads();
    const float am = fmaxf(fmaxf(s_red[0], s_red[1]), fmaxf(s_red[2], s_red[3]));

    const float scale  = fmaxf(am * (1.0f / 127.0f), 1e-8f);
    const float iscale = 1.0f / scale;

    const int ngroups = (nrows + WPB - 1) / WPB;
    int g = blockIdx.x;
    if (g >= ngroups) return;

    int row  = g * WPB + wave;
    bool act = row < nrows;
    c8 a = {};
    float f = 0.0f;
    if (act) {
        a = reinterpret_cast<const c8*>(svq + (size_t)row * ROW_LEN)[lane];
        f = rowg[row] * iscale;
    }
    while (true) {
        const int gn   = g + NB;
        const int rown = gn * WPB + wave;
        const bool actn = (gn < ngroups) && (rown < nrows);
        c8 an8 = {};
        float fn = 0.0f;
        if (actn) {
            an8 = reinterpret_cast<const c8*>(svq + (size_t)rown * ROW_LEN)[lane];
            fn  = rowg[rown] * iscale;
        }
        if (act) {
            float o[8];
#pragma unroll
            for (int j = 0; j < 8; ++j) {
                float q = fminf(fmaxf(rintf((float)a[j] * f), -127.0f), 127.0f);
                o[j] = q * scale;
            }
            f4* op = reinterpret_cast<f4*>(out + (size_t)row * ROW_LEN);
            f4 w0 = {o[0], o[1], o[2], o[3]};
            f4 w1 = {o[4], o[5], o[6], o[7]};
            __builtin_nontemporal_store(w0, op + lane);
            __builtin_nontemporal_store(w1, op + lane + 64);
        }
        if (gn >= ngroups) break;
        g = gn; row = rown; act = actn; a = an8; f = fn;
    }
}

extern "C" void kernel_launch(void* const* d_in, const int* in_sizes, int n_in,
                              void* d_out, int out_size, void* d_ws, size_t ws_size,
                              hipStream_t stream) {
    const float* scores    = (const float*)d_in[0];
    const float* coeffs_m  = (const float*)d_in[1];
    const float* coeffs_c  = (const float*)d_in[2];
    const float* intervals = (const float*)d_in[3];
    float* out = (float*)d_out;

    const int nrows = in_sizes[0] / ROW_LEN;

    // ws layout (all regions fully overwritten every launch):
    //   [0, NB*4)            slots
    //   [128KB, +nrows*4)    rowg
    //   [1MB, +nrows*512)    svq (s8, ~25 MB)
    float* slots = (float*)d_ws;
    float* rowg  = (float*)((char*)d_ws + (128 << 10));
    char*  svq   = (char*)d_ws + (1 << 20);

    pla_pass0<<<NB, THREADS, 0, stream>>>(
        scores, coeffs_m, coeffs_c, intervals, svq, rowg, slots, nrows);
    pla_pass1<<<NB, THREADS, 0, stream>>>(svq, rowg, slots, out, nrows);
}

// Round 13
// 50.826 us; speedup vs baseline: 1.0768x; 1.0768x over previous
//
#include <hip/hip_runtime.h>

#define THREADS 256
#define WPB 4
#define ROW_LEN 512
#define NB 2048            // grid-stride block count: 2048*4 waves = 8192 wave slots

typedef float f4 __attribute__((ext_vector_type(4)));
typedef char  c8 __attribute__((ext_vector_type(8)));

__device__ __forceinline__ float wave_reduce_max(float v) {
#pragma unroll
    for (int o = 32; o > 0; o >>= 1) v = fmaxf(v, __shfl_xor(v, o));
    return v;
}
__device__ __forceinline__ float wave_reduce_sum(float v) {
#pragma unroll
    for (int o = 32; o > 0; o >>= 1) v += __shfl_xor(v, o);
    return v;
}

// pass 0: only reader of scores. TRIPS>0 -> compile-time trip count, fully
// unrolled, no bounds checks (compiler interleaves the independent rows'
// loads/VALU under each row's serial shuffle-reduce chains). TRIPS==0 ->
// generic bounds-checked loop.
template <int TRIPS>
__global__ __launch_bounds__(THREADS) void pla_pass0(
    const float* __restrict__ scores,
    const float* __restrict__ coeffs_m,
    const float* __restrict__ coeffs_c,
    const float* __restrict__ intervals,
    char* __restrict__ svq,            // [nrows*512] s8
    float* __restrict__ rowg,          // [nrows] g_r
    float* __restrict__ slots,         // [NB], fully overwritten
    int nrows)
{
    __shared__ float2 s_mc[12];
    __shared__ float  s_a[13];         // interval lower edges + inf guard
    __shared__ float  s_bm[WPB];

    const int tid = threadIdx.x;
    if (tid < 12) {
        s_mc[tid] = make_float2(coeffs_m[tid], coeffs_c[tid]);
        s_a[tid]  = intervals[tid];
    }
    if (tid == 12) s_a[12] = __builtin_inff();
    __syncthreads();

    const int wave = tid >> 6;
    const int lane = tid & 63;

    const float c10 = coeffs_c[10];
    const float k0  = 127.0f / c10;

    float bmax = 0.0f;                                  // per-wave (lane0) candidate

    auto do_row = [&](int row) {
        const float4* rp = reinterpret_cast<const float4*>(scores + (size_t)row * ROW_LEN);
        float4 v0 = rp[lane];
        float4 v1 = rp[lane + 64];
        float x[8] = {v0.x, v0.y, v0.z, v0.w, v1.x, v1.y, v1.z, v1.w};

        float mx = fmaxf(fmaxf(fmaxf(x[0], x[1]), fmaxf(x[2], x[3])),
                         fmaxf(fmaxf(x[4], x[5]), fmaxf(x[6], x[7])));
        mx = wave_reduce_max(mx);

        float sum = 0.0f;
        c8 q;
#pragma unroll
        for (int j = 0; j < 8; ++j) {
            float sh = x[j] - mx;                   // <= 0; |sh| < 32 here
            float t = rintf(sh * 67108864.0f);      // Q32.26 snap (2^31 clamp never binds)
            float fx = t * 1.4901161193847656e-8f;  // * 2^-26 exact
            float xc = fmaxf(fx, -10.0f);           // fx <= 0 structurally

            // exact searchsorted: fused uniform-width guess + edge-table correction.
            // fmaf(xc,1.2f,12.0f) ranges [-5e-7, 12]; trunc of tiny negative -> 0,
            // so no max(gi,0) needed.
            int gi = (int)fmaf(xc, 1.2f, 12.0f);
            gi = min(gi, 11);
            if (xc < s_a[gi])            gi -= 1;
            else if (xc >= s_a[gi + 1])  gi += 1;
            int idx = min(gi, 10);                  // reference clamp to len-2

            float2 p = s_mc[idx];
            float ev = fmaf(p.x, xc, p.y);          // same contraction -O3 emitted before
            sum += ev;
            q[j] = (char)(int)rintf(ev * k0);       // scale-free: store before sum chain
        }
        reinterpret_cast<c8*>(svq + (size_t)row * ROW_LEN)[lane] = q;

        sum = wave_reduce_sum(sum);
        const float inv = 1.0f / (sum + 1e-9f);
        if (lane == 0) {
            rowg[row] = c10 * inv * (1.0f / 127.0f);
            bmax = fmaxf(bmax, c10 * inv);          // row absmax candidate
        }
    };

    if constexpr (TRIPS > 0) {
#pragma unroll
        for (int t = 0; t < TRIPS; ++t)
            do_row((blockIdx.x + t * NB) * WPB + wave);
    } else {
        const int ngroups = (nrows + WPB - 1) / WPB;
        for (int g = blockIdx.x; g < ngroups; g += NB) {
            const int row = g * WPB + wave;
            if (row < nrows) do_row(row);
        }
    }

    if (lane == 0) s_bm[wave] = bmax;
    __syncthreads();
    if (tid == 0) {
        float bm = fmaxf(fmaxf(s_bm[0], s_bm[1]), fmaxf(s_bm[2], s_bm[3]));
        slots[blockIdx.x] = bm;
    }
}

// pass 1: prologue reduces slots[NB] block-locally -> scale; then per row:
// s8 -> q = clamp(rint(s8 * g_r * iscale)) -> nt-store q*scale.
template <int TRIPS>
__global__ __launch_bounds__(THREADS) void pla_pass1(
    const char* __restrict__ svq,
    const float* __restrict__ rowg,
    const float* __restrict__ slots,
    float* __restrict__ out,
    int nrows)
{
    __shared__ float s_red[WPB];
    const int tid  = threadIdx.x;
    const int wave = tid >> 6;
    const int lane = tid & 63;

    // block-local global-absmax reduce (identical result in every block)
    float m = 0.0f;
    for (int i = tid; i < NB; i += THREADS) m = fmaxf(m, slots[i]);
    m = wave_reduce_max(m);
    if (lane == 0) s_red[wave] = m;
    __syncthreads();
    const float am = fmaxf(fmaxf(s_red[0], s_red[1]), fmaxf(s_red[2], s_red[3]));

    const float scale  = fmaxf(am * (1.0f / 127.0f), 1e-8f);
    const float iscale = 1.0f / scale;

    auto do_row = [&](int row) {
        const float f = rowg[row] * iscale;         // per-row requant factor
        c8 a = reinterpret_cast<const c8*>(svq + (size_t)row * ROW_LEN)[lane];

        float o[8];
#pragma unroll
        for (int j = 0; j < 8; ++j) {
            float q = fminf(fmaxf(rintf((float)a[j] * f), -127.0f), 127.0f);
            o[j] = q * scale;
        }
        f4* op = reinterpret_cast<f4*>(out + (size_t)row * ROW_LEN);
        f4 w0 = {o[0], o[1], o[2], o[3]};
        f4 w1 = {o[4], o[5], o[6], o[7]};
        __builtin_nontemporal_store(w0, op + lane);
        __builtin_nontemporal_store(w1, op + lane + 64);
    };

    if constexpr (TRIPS > 0) {
#pragma unroll
        for (int t = 0; t < TRIPS; ++t)
            do_row((blockIdx.x + t * NB) * WPB + wave);
    } else {
        const int ngroups = (nrows + WPB - 1) / WPB;
        for (int g = blockIdx.x; g < ngroups; g += NB) {
            const int row = g * WPB + wave;
            if (row < nrows) do_row(row);
        }
    }
}

extern "C" void kernel_launch(void* const* d_in, const int* in_sizes, int n_in,
                              void* d_out, int out_size, void* d_ws, size_t ws_size,
                              hipStream_t stream) {
    const float* scores    = (const float*)d_in[0];
    const float* coeffs_m  = (const float*)d_in[1];
    const float* coeffs_c  = (const float*)d_in[2];
    const float* intervals = (const float*)d_in[3];
    float* out = (float*)d_out;

    const int nrows = in_sizes[0] / ROW_LEN;

    // ws layout (all regions fully overwritten every launch):
    //   [0, NB*4)            slots
    //   [128KB, +nrows*4)    rowg
    //   [1MB, +nrows*512)    svq (s8, ~25 MB)
    float* slots = (float*)d_ws;
    float* rowg  = (float*)((char*)d_ws + (128 << 10));
    char*  svq   = (char*)d_ws + (1 << 20);

    // Exact-shape fast path: nrows = 49152 -> ngroups = 12288 = 6*NB, no remainder.
    const bool even = (nrows % WPB) == 0;
    const int  trips = (even && ((nrows / WPB) % NB) == 0) ? (nrows / WPB) / NB : 0;

    if (trips == 6) {
        pla_pass0<6><<<NB, THREADS, 0, stream>>>(
            scores, coeffs_m, coeffs_c, intervals, svq, rowg, slots, nrows);
        pla_pass1<6><<<NB, THREADS, 0, stream>>>(svq, rowg, slots, out, nrows);
    } else {
        pla_pass0<0><<<NB, THREADS, 0, stream>>>(
            scores, coeffs_m, coeffs_c, intervals, svq, rowg, slots, nrows);
        pla_pass1<0><<<NB, THREADS, 0, stream>>>(svq, rowg, slots, out, nrows);
    }
}